// Round 16
// baseline (1393.201 us; speedup 1.0000x reference)
//
#include <hip/hip_runtime.h>
#include <stdint.h>

// MessagePassingConvolution: E=500000, N=25000, C=32.
// Round 15: round-14 with the cvt_pkrtz type fix (bit_cast the __fp16x2
// return directly). Structure: r13's per-wave shape (LDS weights) at
// 3 blocks/CU: block=256, LDS 28KB = 12KB phased weights + 16KB hp half,
// h pairs 0..15 in VGPRs (static indices), v_cvt_pk_bf16_f32 msg pack.

#define NCH 256

constexpr float INV_SQRT32 = 0.17677669529663687f; // 1/sqrt(32)
constexpr float INV_8      = 0.125f;               // 1/sqrt(64)
constexpr float INV_SQRT3  = 0.57735026918962576f;
constexpr float SCALE      = 0.22360679774997896f; // 1/sqrt(20)

typedef _Float16 h2_t __attribute__((ext_vector_type(2)));
typedef unsigned int u32x4 __attribute__((ext_vector_type(4)));
typedef unsigned int u32x2 __attribute__((ext_vector_type(2)));

__device__ __forceinline__ float f4c(const float4 v, int c) {
    return c == 0 ? v.x : c == 1 ? v.y : c == 2 ? v.z : v.w;
}
__device__ __forceinline__ float bl(unsigned int u) { return __uint_as_float(u << 16); }
__device__ __forceinline__ float bh(unsigned int u) { return __uint_as_float(u & 0xffff0000u); }

// single-instruction f32x2 -> packed bf16 (RNE), replaces 8-op manual pack
__device__ __forceinline__ unsigned int pack2(float a, float b) {
    unsigned int r;
    asm("v_cvt_pk_bf16_f32 %0, %1, %2" : "=v"(r) : "v"(a), "v"(b));
    return r;
}
// f32 pair -> packed f16 (RTZ), single v_cvt_pkrtz_f16_f32
__device__ __forceinline__ unsigned int packh2(float a, float b) {
    return __builtin_bit_cast(unsigned int, __builtin_amdgcn_cvt_pkrtz(a, b));
}
// pre-pack kernel: bit-exact f16 RNE via compiler casts
__device__ __forceinline__ unsigned int packh2_rne(float a, float b) {
    h2_t v; v[0] = (_Float16)a; v[1] = (_Float16)b;
    return __builtin_bit_cast(unsigned int, v);
}
__device__ __forceinline__ float dot2u(unsigned int a, unsigned int b, float c) {
#if __has_builtin(__builtin_amdgcn_fdot2)
    return __builtin_amdgcn_fdot2(__builtin_bit_cast(h2_t, a),
                                  __builtin_bit_cast(h2_t, b), c, false);
#else
    h2_t x = __builtin_bit_cast(h2_t, a), y = __builtin_bit_cast(h2_t, b);
    return fmaf((float)x[0], (float)y[0], fmaf((float)x[1], (float)y[1], c));
#endif
}
__device__ __forceinline__ float siluf(float x) {
    const float d = 1.f + __expf(-x);
#if __has_builtin(__builtin_amdgcn_rcpf)
    return x * __builtin_amdgcn_rcpf(d);
#else
    return x / d;
#endif
}
__device__ __forceinline__ void st4(unsigned int* p, unsigned int a,
                                    unsigned int b, unsigned int c, unsigned int d) {
    u32x4 v; v[0] = a; v[1] = b; v[2] = c; v[3] = d;
    *(u32x4*)p = v;
}

// ---------------- weight pre-pack: f32 -> f16 pairs along K ----------------
// wp layout: [0,1024) W1p(16x64)  [1024,3072) W2p(32x64)
//            [3072,5120) W3A(32x64 = W3 cols 0..63)  [5120,7168) W3B(cols 64..127)
__global__ void wconv_kernel(const float* __restrict__ W1, const float* __restrict__ W2,
                             const float* __restrict__ W3, unsigned int* __restrict__ wp) {
    int t = blockIdx.x * 256 + threadIdx.x;
    if (t < 1024) {
        int k = t >> 6, j = t & 63;
        wp[t] = packh2_rne(W1[2 * k * 64 + j], W1[(2 * k + 1) * 64 + j]);
    } else if (t < 3072) {
        int i = t - 1024, k = i >> 6, j = i & 63;
        wp[t] = packh2_rne(W2[2 * k * 64 + j], W2[(2 * k + 1) * 64 + j]);
    } else if (t < 5120) {
        int i = t - 3072, k = i >> 6, j = i & 63;
        wp[t] = packh2_rne(W3[2 * k * 128 + j], W3[(2 * k + 1) * 128 + j]);
    } else if (t < 7168) {
        int i = t - 5120, k = i >> 6, j = i & 63;
        wp[t] = packh2_rne(W3[2 * k * 128 + 64 + j], W3[(2 * k + 1) * 128 + 64 + j]);
    }
}

// ---------------- CSR build ----------------
__global__ void hist_kernel(const int* __restrict__ recv, int* __restrict__ cnt, int E) {
    int e = blockIdx.x * 256 + threadIdx.x;
    if (e < E) atomicAdd(&cnt[recv[e]], 1);
}

__global__ __launch_bounds__(1024) void scan_kernel(const int* __restrict__ cnt,
                                                    int* __restrict__ off, int N) {
    __shared__ int sh[1024];
    __shared__ int sbase;
    if (threadIdx.x == 0) sbase = 0;
    __syncthreads();
    for (int base = 0; base < N; base += 1024) {
        int i = base + threadIdx.x;
        int v = (i < N) ? cnt[i] : 0;
        sh[threadIdx.x] = v;
        __syncthreads();
        #pragma unroll
        for (int d = 1; d < 1024; d <<= 1) {
            int t = (threadIdx.x >= d) ? sh[threadIdx.x - d] : 0;
            __syncthreads();
            sh[threadIdx.x] += t;
            __syncthreads();
        }
        int incl = sh[threadIdx.x];
        int bb = sbase;
        if (i < N) off[i] = bb + incl - v;
        __syncthreads();
        if (threadIdx.x == 1023) sbase = bb + incl;
        __syncthreads();
    }
    if (threadIdx.x == 0) off[N] = sbase;
}

// ---------------- Phase 1: f16-dot2 MLP + bf16 message store + scatter ----------------
__global__ __launch_bounds__(256, 2) void msg_kernel(
    const float* __restrict__ edge_feats,   // (E,128)
    const float* __restrict__ edge_attrs,   // (E,4)
    const int*   __restrict__ receivers,
    const unsigned int* __restrict__ wp,    // packed f16 weights (global, 16B aligned)
    const int* __restrict__ off, int* __restrict__ cursor, int* __restrict__ perm,
    unsigned int* __restrict__ msg,         // (E,128) u32 = 256 bf16 channels
    int E)
{
    __shared__ u32x4 wsh4[768];             // 12 KB weight region (phased reuse)
    __shared__ unsigned int hp[16][256];    // 16 KB: h pairs 16..31
    unsigned int* wsh = (unsigned int*)wsh4;

    const int tid = threadIdx.x;
    const u32x4* wp4 = (const u32x4*)wp;

    // ---- stage 0: W1 (dwords 0..1024) + W2 (1024..3072) = 768 u32x4 ----
    #pragma unroll
    for (int i = 0; i < 3; ++i) wsh4[i * 256 + tid] = wp4[i * 256 + tid];
    __syncthreads();

    const int e = blockIdx.x * 256 + tid;
    const bool valid = (e < E);
    const int ec = valid ? e : (E - 1);
    const float4* row4 = (const float4*)(edge_feats + (size_t)ec * 128);

    const float4 ea = *(const float4*)(edge_attrs + (size_t)ec * 4);
    const float s0 = ea.x, v0x = ea.y, v0y = ea.z, v0z = ea.w;

    if (valid) {
        const int r = receivers[e];
        const int pos = off[r] + atomicAdd(&cursor[r], 1);
        perm[pos] = e;
    }

    float acc[64];
    unsigned int hreg[16];                  // h pairs 0..15 (all static indices)

    // ---- layer 1: h1 = silu((s @ W1)/sqrt(32)) ----
    #pragma unroll
    for (int j = 0; j < 64; ++j) acc[j] = 0.f;
    #pragma unroll
    for (int kk = 0; kk < 8; ++kk) {
        const float4 r4 = row4[kk];
        const unsigned int p0 = packh2(r4.x, r4.y);
        const unsigned int p1 = packh2(r4.z, r4.w);
        const unsigned int* w = wsh + kk * 128;
        #pragma unroll
        for (int j = 0; j < 64; ++j) acc[j] = dot2u(p0, w[j], acc[j]);
        #pragma unroll
        for (int j = 0; j < 64; ++j) acc[j] = dot2u(p1, w[64 + j], acc[j]);
    }
    #pragma unroll
    for (int p = 0; p < 16; ++p)
        hreg[p] = packh2(siluf(acc[2 * p] * INV_SQRT32), siluf(acc[2 * p + 1] * INV_SQRT32));
    #pragma unroll
    for (int p = 16; p < 32; ++p)
        hp[p - 16][tid] = packh2(siluf(acc[2 * p] * INV_SQRT32), siluf(acc[2 * p + 1] * INV_SQRT32));

    // ---- layer 2: h2 = silu((h1 @ W2)/8) ----
    #pragma unroll
    for (int j = 0; j < 64; ++j) acc[j] = 0.f;
    #pragma unroll
    for (int k = 0; k < 16; ++k) {
        const unsigned int u = hreg[k];
        const unsigned int* w = wsh + 1024 + k * 64;
        #pragma unroll
        for (int j = 0; j < 64; ++j) acc[j] = dot2u(u, w[j], acc[j]);
    }
    #pragma unroll
    for (int k = 16; k < 32; ++k) {
        const unsigned int u = hp[k - 16][tid];
        const unsigned int* w = wsh + 1024 + k * 64;
        #pragma unroll
        for (int j = 0; j < 64; ++j) acc[j] = dot2u(u, w[j], acc[j]);
    }
    #pragma unroll
    for (int p = 0; p < 16; ++p)
        hreg[p] = packh2(siluf(acc[2 * p] * INV_8), siluf(acc[2 * p + 1] * INV_8));
    #pragma unroll
    for (int p = 16; p < 32; ++p)
        hp[p - 16][tid] = packh2(siluf(acc[2 * p] * INV_8), siluf(acc[2 * p + 1] * INV_8));

    // ---- stage 1: W3A (dwords 3072..5120) -> wsh[0..2048) ----
    __syncthreads();                        // all W1/W2 reads done
    wsh4[tid] = wp4[768 + tid];
    wsh4[256 + tid] = wp4[1024 + tid];
    __syncthreads();

    unsigned int* mp = msg + (size_t)ec * 128;

    // ---- pass A: mix[0:64] ----
    #pragma unroll
    for (int j = 0; j < 64; ++j) acc[j] = 0.f;
    #pragma unroll
    for (int k = 0; k < 16; ++k) {
        const unsigned int u = hreg[k];
        const unsigned int* w = wsh + k * 64;
        #pragma unroll
        for (int j = 0; j < 64; ++j) acc[j] = dot2u(u, w[j], acc[j]);
    }
    #pragma unroll
    for (int k = 16; k < 32; ++k) {
        const unsigned int u = hp[k - 16][tid];
        const unsigned int* w = wsh + k * 64;
        #pragma unroll
        for (int j = 0; j < 64; ++j) acc[j] = dot2u(u, w[j], acc[j]);
    }
    float4 rv[8];
    #pragma unroll
    for (int i = 0; i < 8; ++i) rv[i] = row4[i];

    {
        unsigned int arr[32];
        #pragma unroll
        for (int w = 0; w < 16; ++w) {          // ch 0..31: s_j * s0 * m_j
            const int c0 = 2 * w, c1 = c0 + 1;
            const float a = f4c(rv[c0 >> 2], c0 & 3) * s0 * acc[c0] * (INV_8 * SCALE);
            const float b = f4c(rv[c1 >> 2], c1 & 3) * s0 * acc[c1] * (INV_8 * SCALE);
            arr[w] = pack2(a, b);
        }
        #pragma unroll
        for (int g = 0; g < 8; ++g) {           // ch 32..63: dot(v_j, v0)/sqrt3 * m
            const float4 q0 = row4[8 + 3 * g], q1 = row4[8 + 3 * g + 1], q2 = row4[8 + 3 * g + 2];
            const float d0 = q0.x * v0x + q0.y * v0y + q0.z * v0z;
            const float d1 = q0.w * v0x + q1.x * v0y + q1.y * v0z;
            const float d2 = q1.z * v0x + q1.w * v0y + q2.x * v0z;
            const float d3 = q2.y * v0x + q2.z * v0y + q2.w * v0z;
            const float sc = INV_8 * SCALE * INV_SQRT3;
            arr[16 + 2 * g]     = pack2(d0 * acc[32 + 4 * g] * sc,     d1 * acc[32 + 4 * g + 1] * sc);
            arr[16 + 2 * g + 1] = pack2(d2 * acc[32 + 4 * g + 2] * sc, d3 * acc[32 + 4 * g + 3] * sc);
        }
        if (valid) {
            #pragma unroll
            for (int q = 0; q < 8; ++q)
                st4(mp + q * 4, arr[4 * q], arr[4 * q + 1], arr[4 * q + 2], arr[4 * q + 3]);
        }
    }

    // ---- stage 2: W3B (dwords 5120..7168) -> wsh[0..2048) ----
    __syncthreads();                        // all W3A reads done
    wsh4[tid] = wp4[1280 + tid];
    wsh4[256 + tid] = wp4[1536 + tid];
    __syncthreads();

    // ---- pass B: mix[64:128] ----
    #pragma unroll
    for (int j = 0; j < 64; ++j) acc[j] = 0.f;
    #pragma unroll
    for (int k = 0; k < 16; ++k) {
        const unsigned int u = hreg[k];
        const unsigned int* w = wsh + k * 64;
        #pragma unroll
        for (int j = 0; j < 64; ++j) acc[j] = dot2u(u, w[j], acc[j]);
    }
    #pragma unroll
    for (int k = 16; k < 32; ++k) {
        const unsigned int u = hp[k - 16][tid];
        const unsigned int* w = wsh + k * 64;
        #pragma unroll
        for (int j = 0; j < 64; ++j) acc[j] = dot2u(u, w[j], acc[j]);
    }
    {
        unsigned int arr2[48];
        #pragma unroll
        for (int w = 0; w < 48; ++w) {          // ch 64..159: s_j * v0_d * m
            const int f0 = 2 * w, f1 = f0 + 1;
            const int j0 = f0 / 3, dd0 = f0 % 3, j1 = f1 / 3, dd1 = f1 % 3;
            const float a = f4c(rv[j0 >> 2], j0 & 3) * acc[j0] * (INV_8 * SCALE) *
                            (dd0 == 0 ? v0x : dd0 == 1 ? v0y : v0z);
            const float b = f4c(rv[j1 >> 2], j1 & 3) * acc[j1] * (INV_8 * SCALE) *
                            (dd1 == 0 ? v0x : dd1 == 1 ? v0y : v0z);
            arr2[w] = pack2(a, b);
        }
        if (valid) {
            #pragma unroll
            for (int q = 0; q < 12; ++q)
                st4(mp + 32 + q * 4, arr2[4 * q], arr2[4 * q + 1], arr2[4 * q + 2], arr2[4 * q + 3]);
        }
        #pragma unroll
        for (int g = 0; g < 8; ++g) {           // ch 160..255: v_j[d] * s0 * m
            const float4 q0 = row4[8 + 3 * g], q1 = row4[8 + 3 * g + 1], q2 = row4[8 + 3 * g + 2];
            const float f[12] = {q0.x, q0.y, q0.z, q0.w, q1.x, q1.y, q1.z, q1.w,
                                 q2.x, q2.y, q2.z, q2.w};
            #pragma unroll
            for (int p = 0; p < 6; ++p) {
                const int i0 = 2 * p, i1 = i0 + 1;
                const float a = f[i0] * s0 * acc[32 + (g * 12 + i0) / 3] * (INV_8 * SCALE);
                const float b = f[i1] * s0 * acc[32 + (g * 12 + i1) / 3] * (INV_8 * SCALE);
                arr2[6 * g + p] = pack2(a, b);
            }
        }
        if (valid) {
            #pragma unroll
            for (int q = 0; q < 12; ++q)
                st4(mp + 80 + q * 4, arr2[4 * q], arr2[4 * q + 1], arr2[4 * q + 2], arr2[4 * q + 3]);
        }
    }
}

// ---------------- Phase 2: gather (wave per node, lane = 4 channels) ----------------
__global__ __launch_bounds__(256) void gather_kernel(
    const unsigned short* __restrict__ msg, const int* __restrict__ off,
    const int* __restrict__ perm, float* __restrict__ out, int N)
{
    const int wid = threadIdx.x >> 6;
    const int lane = threadIdx.x & 63;
    const int n = blockIdx.x * 4 + wid;
    if (n >= N) return;
    const int beg = off[n], end = off[n + 1];
    float a0 = 0.f, a1 = 0.f, a2 = 0.f, a3 = 0.f;
    int i = beg;
    for (; i + 1 < end; i += 2) {
        const int e1 = perm[i], e2 = perm[i + 1];
        const u32x2 va = *(const u32x2*)(msg + (size_t)e1 * 256 + lane * 4);
        const u32x2 vb = *(const u32x2*)(msg + (size_t)e2 * 256 + lane * 4);
        a0 += bl(va[0]) + bl(vb[0]);
        a1 += bh(va[0]) + bh(vb[0]);
        a2 += bl(va[1]) + bl(vb[1]);
        a3 += bh(va[1]) + bh(vb[1]);
    }
    if (i < end) {
        const int e1 = perm[i];
        const u32x2 va = *(const u32x2*)(msg + (size_t)e1 * 256 + lane * 4);
        a0 += bl(va[0]); a1 += bh(va[0]); a2 += bl(va[1]); a3 += bh(va[1]);
    }
    *(float4*)(out + (size_t)n * NCH + lane * 4) = make_float4(a0, a1, a2, a3);
}

// ---------------- Fallback (atomic path, if ws too small) ----------------
__global__ __launch_bounds__(256, 2) void mpconv_atomic_kernel(
    const float* __restrict__ edge_feats, const float* __restrict__ edge_attrs,
    const int* __restrict__ receivers,
    const float* __restrict__ W1, const float* __restrict__ W2, const float* __restrict__ W3,
    float* __restrict__ out, int E)
{
    __shared__ float hbuf[64][256];
    const int tid = threadIdx.x;
    const int e = blockIdx.x * 256 + tid;
    if (e >= E) return;
    const float* row = edge_feats + (size_t)e * 128;
    float acc[64];
    #pragma unroll
    for (int j = 0; j < 64; ++j) acc[j] = 0.f;
    for (int k = 0; k < 32; ++k) {
        const float sk = row[k];
        const float* w = W1 + k * 64;
        #pragma unroll
        for (int j = 0; j < 64; ++j) acc[j] = fmaf(sk, w[j], acc[j]);
    }
    #pragma unroll
    for (int j = 0; j < 64; ++j) {
        const float x = acc[j] * INV_SQRT32;
        hbuf[j][tid] = x / (1.f + __expf(-x));
    }
    #pragma unroll
    for (int j = 0; j < 64; ++j) acc[j] = 0.f;
    for (int k = 0; k < 64; ++k) {
        const float hk = hbuf[k][tid];
        const float* w = W2 + k * 64;
        #pragma unroll
        for (int j = 0; j < 64; ++j) acc[j] = fmaf(hk, w[j], acc[j]);
    }
    #pragma unroll
    for (int j = 0; j < 64; ++j) {
        const float x = acc[j] * INV_8;
        hbuf[j][tid] = x / (1.f + __expf(-x));
    }
    const float4 ea = *reinterpret_cast<const float4*>(edge_attrs + (size_t)e * 4);
    const float s0 = ea.x, v0x = ea.y, v0y = ea.z, v0z = ea.w;
    const int r = receivers[e];
    float* o = out + (size_t)r * NCH;
    #pragma unroll
    for (int j = 0; j < 64; ++j) acc[j] = 0.f;
    for (int k = 0; k < 64; ++k) {
        const float hk = hbuf[k][tid];
        const float* w = W3 + k * 128;
        #pragma unroll
        for (int j = 0; j < 64; ++j) acc[j] = fmaf(hk, w[j], acc[j]);
    }
    #pragma unroll
    for (int j = 0; j < 32; ++j)
        unsafeAtomicAdd(o + j, row[j] * s0 * acc[j] * (INV_8 * SCALE));
    #pragma unroll
    for (int j = 32; j < 64; ++j) {
        const float* vr = row + 32 + (j - 32) * 3;
        const float dot = vr[0] * v0x + vr[1] * v0y + vr[2] * v0z;
        unsafeAtomicAdd(o + j, dot * acc[j] * (INV_8 * SCALE * INV_SQRT3));
    }
    #pragma unroll
    for (int j = 0; j < 64; ++j) acc[j] = 0.f;
    for (int k = 0; k < 64; ++k) {
        const float hk = hbuf[k][tid];
        const float* w = W3 + k * 128 + 64;
        #pragma unroll
        for (int j = 0; j < 64; ++j) acc[j] = fmaf(hk, w[j], acc[j]);
    }
    #pragma unroll
    for (int j = 0; j < 32; ++j) {
        const float sj = row[j] * acc[j] * (INV_8 * SCALE);
        unsafeAtomicAdd(o + 64 + j * 3 + 0, sj * v0x);
        unsafeAtomicAdd(o + 64 + j * 3 + 1, sj * v0y);
        unsafeAtomicAdd(o + 64 + j * 3 + 2, sj * v0z);
    }
    #pragma unroll
    for (int j = 32; j < 64; ++j) {
        const float m = acc[j] * (INV_8 * SCALE) * s0;
        const float* vr = row + 32 + (j - 32) * 3;
        unsafeAtomicAdd(o + 64 + j * 3 + 0, vr[0] * m);
        unsafeAtomicAdd(o + 64 + j * 3 + 1, vr[1] * m);
        unsafeAtomicAdd(o + 64 + j * 3 + 2, vr[2] * m);
    }
}

extern "C" void kernel_launch(void* const* d_in, const int* in_sizes, int n_in,
                              void* d_out, int out_size, void* d_ws, size_t ws_size,
                              hipStream_t stream) {
    const float* edge_feats = (const float*)d_in[0];
    const float* edge_attrs = (const float*)d_in[1];
    const int*   receivers  = (const int*)d_in[2];
    const float* W1 = (const float*)d_in[4];
    const float* W2 = (const float*)d_in[5];
    const float* W3 = (const float*)d_in[6];

    const int E = in_sizes[0] / 128;
    const int N = out_size / NCH;

    const size_t wb_bytes  = 7168 * sizeof(unsigned int);              // 28672, 16B mult
    const size_t msg_bytes = (size_t)E * NCH * sizeof(unsigned short); // bf16
    const size_t need = wb_bytes + msg_bytes + (size_t)(3 * N + 1 + E) * sizeof(int);

    if (ws_size >= need) {
        unsigned int* wp  = (unsigned int*)d_ws;                       // 16B aligned
        unsigned int* msg = (unsigned int*)((char*)d_ws + wb_bytes);   // 16B aligned
        int* cnt    = (int*)((char*)msg + msg_bytes);
        int* cursor = cnt + N;
        int* off    = cursor + N;
        int* perm   = off + N + 1;

        wconv_kernel<<<28, 256, 0, stream>>>(W1, W2, W3, wp);
        hipMemsetAsync(cnt, 0, (size_t)2 * N * sizeof(int), stream);
        hist_kernel<<<(E + 255) / 256, 256, 0, stream>>>(receivers, cnt, E);
        scan_kernel<<<1, 1024, 0, stream>>>(cnt, off, N);
        msg_kernel<<<(E + 255) / 256, 256, 0, stream>>>(
            edge_feats, edge_attrs, receivers, wp,
            off, cursor, perm, msg, E);
        gather_kernel<<<(N + 3) / 4, 256, 0, stream>>>(
            (const unsigned short*)msg, off, perm, (float*)d_out, N);
    } else {
        hipMemsetAsync(d_out, 0, (size_t)out_size * sizeof(float), stream);
        mpconv_atomic_kernel<<<(E + 255) / 256, 256, 0, stream>>>(
            edge_feats, edge_attrs, receivers, W1, W2, W3, (float*)d_out, E);
    }
}

// Round 17
// 437.782 us; speedup vs baseline: 3.1824x; 3.1824x over previous
//
#include <hip/hip_runtime.h>
#include <stdint.h>

// MessagePassingConvolution: E=500000, N=25000, C=32.
// Round 16: attack the uniform 3x VALU overhead seen in ALL passing rounds
// (VALU-busy ~145us vs ~50us dot2 floor, invariant to weights/occupancy/caps).
// Suspects: acc[64] -> AGPR shuffle (VGPR_Count 64-96 can't hold it) and
// ~60-100KB unrolled code thrashing I-cache. Fix both: 32-wide half-passes
// (acc[32]; epilogue splits cleanly on 32-wide mix blocks) + #pragma unroll
// 1/4 k-loops (~13KB code). Base = r10 (global wp, hp LDS, lb(256,2)).
// Packed converts (v_cvt_pk_bf16_f32 / cvt_pkrtz) kept from r15 (numerics
// validated there: absmax 0.031; r15's regression was spill, not numerics).

#define NCH 256

constexpr float INV_SQRT32 = 0.17677669529663687f; // 1/sqrt(32)
constexpr float INV_8      = 0.125f;               // 1/sqrt(64)
constexpr float INV_SQRT3  = 0.57735026918962576f;
constexpr float SCALE      = 0.22360679774997896f; // 1/sqrt(20)

typedef _Float16 h2_t __attribute__((ext_vector_type(2)));
typedef unsigned int u32x4 __attribute__((ext_vector_type(4)));
typedef unsigned int u32x2 __attribute__((ext_vector_type(2)));

__device__ __forceinline__ float f4c(const float4 v, int c) {
    return c == 0 ? v.x : c == 1 ? v.y : c == 2 ? v.z : v.w;
}
__device__ __forceinline__ float bl(unsigned int u) { return __uint_as_float(u << 16); }
__device__ __forceinline__ float bh(unsigned int u) { return __uint_as_float(u & 0xffff0000u); }

__device__ __forceinline__ unsigned int pack2(float a, float b) {
    unsigned int r;
    asm("v_cvt_pk_bf16_f32 %0, %1, %2" : "=v"(r) : "v"(a), "v"(b));
    return r;
}
__device__ __forceinline__ unsigned int packh2(float a, float b) {
    return __builtin_bit_cast(unsigned int, __builtin_amdgcn_cvt_pkrtz(a, b));
}
__device__ __forceinline__ unsigned int packh2_rne(float a, float b) {
    h2_t v; v[0] = (_Float16)a; v[1] = (_Float16)b;
    return __builtin_bit_cast(unsigned int, v);
}
__device__ __forceinline__ float dot2u(unsigned int a, unsigned int b, float c) {
#if __has_builtin(__builtin_amdgcn_fdot2)
    return __builtin_amdgcn_fdot2(__builtin_bit_cast(h2_t, a),
                                  __builtin_bit_cast(h2_t, b), c, false);
#else
    h2_t x = __builtin_bit_cast(h2_t, a), y = __builtin_bit_cast(h2_t, b);
    return fmaf((float)x[0], (float)y[0], fmaf((float)x[1], (float)y[1], c));
#endif
}
__device__ __forceinline__ float siluf(float x) {
    const float d = 1.f + __expf(-x);
#if __has_builtin(__builtin_amdgcn_rcpf)
    return x * __builtin_amdgcn_rcpf(d);
#else
    return x / d;
#endif
}
__device__ __forceinline__ void st4(unsigned int* p, unsigned int a,
                                    unsigned int b, unsigned int c, unsigned int d) {
    u32x4 v; v[0] = a; v[1] = b; v[2] = c; v[3] = d;
    *(u32x4*)p = v;
}

// ---------------- weight pre-pack: f32 -> f16 pairs along K ----------------
// wp layout: [0,1024) W1p(16x64)  [1024,3072) W2p(32x64)
//            [3072,5120) W3A(32x64 = W3 cols 0..63)  [5120,7168) W3B(cols 64..127)
__global__ void wconv_kernel(const float* __restrict__ W1, const float* __restrict__ W2,
                             const float* __restrict__ W3, unsigned int* __restrict__ wp) {
    int t = blockIdx.x * 256 + threadIdx.x;
    if (t < 1024) {
        int k = t >> 6, j = t & 63;
        wp[t] = packh2_rne(W1[2 * k * 64 + j], W1[(2 * k + 1) * 64 + j]);
    } else if (t < 3072) {
        int i = t - 1024, k = i >> 6, j = i & 63;
        wp[t] = packh2_rne(W2[2 * k * 64 + j], W2[(2 * k + 1) * 64 + j]);
    } else if (t < 5120) {
        int i = t - 3072, k = i >> 6, j = i & 63;
        wp[t] = packh2_rne(W3[2 * k * 128 + j], W3[(2 * k + 1) * 128 + j]);
    } else if (t < 7168) {
        int i = t - 5120, k = i >> 6, j = i & 63;
        wp[t] = packh2_rne(W3[2 * k * 128 + 64 + j], W3[(2 * k + 1) * 128 + 64 + j]);
    }
}

// ---------------- CSR build ----------------
__global__ void hist_kernel(const int* __restrict__ recv, int* __restrict__ cnt, int E) {
    int e = blockIdx.x * 256 + threadIdx.x;
    if (e < E) atomicAdd(&cnt[recv[e]], 1);
}

__global__ __launch_bounds__(1024) void scan_kernel(const int* __restrict__ cnt,
                                                    int* __restrict__ off, int N) {
    __shared__ int sh[1024];
    __shared__ int sbase;
    if (threadIdx.x == 0) sbase = 0;
    __syncthreads();
    for (int base = 0; base < N; base += 1024) {
        int i = base + threadIdx.x;
        int v = (i < N) ? cnt[i] : 0;
        sh[threadIdx.x] = v;
        __syncthreads();
        #pragma unroll
        for (int d = 1; d < 1024; d <<= 1) {
            int t = (threadIdx.x >= d) ? sh[threadIdx.x - d] : 0;
            __syncthreads();
            sh[threadIdx.x] += t;
            __syncthreads();
        }
        int incl = sh[threadIdx.x];
        int bb = sbase;
        if (i < N) off[i] = bb + incl - v;
        __syncthreads();
        if (threadIdx.x == 1023) sbase = bb + incl;
        __syncthreads();
    }
    if (threadIdx.x == 0) off[N] = sbase;
}

// ---------------- Phase 1: f16-dot2 MLP (32-wide half passes) ----------------
__global__ __launch_bounds__(256, 2) void msg_kernel(
    const float* __restrict__ edge_feats,   // (E,128)
    const float* __restrict__ edge_attrs,   // (E,4)
    const int*   __restrict__ receivers,
    const unsigned int* __restrict__ wp,    // packed f16 weights
    const int* __restrict__ off, int* __restrict__ cursor, int* __restrict__ perm,
    unsigned int* __restrict__ msg,         // (E,128) u32 = 256 bf16 channels
    int E)
{
    __shared__ unsigned int hp[32][256];    // h as f16 pairs, 32 KB, thread-private cols

    const unsigned int* wp1  = wp;
    const unsigned int* wp2  = wp + 1024;
    const unsigned int* wp3a = wp + 3072;
    const unsigned int* wp3b = wp + 5120;

    const int tid = threadIdx.x;
    const int e = blockIdx.x * 256 + tid;
    const bool valid = (e < E);
    const int ec = valid ? e : (E - 1);
    const float4* row4 = (const float4*)(edge_feats + (size_t)ec * 128);

    const float4 ea = *(const float4*)(edge_attrs + (size_t)ec * 4);
    const float s0 = ea.x, v0x = ea.y, v0y = ea.z, v0z = ea.w;

    if (valid) {
        const int r = receivers[e];
        const int pos = off[r] + atomicAdd(&cursor[r], 1);
        perm[pos] = e;
    }

    // ---- layer 1: h1 = silu((s @ W1)/sqrt(32)), two 32-col halves ----
    #pragma unroll
    for (int half = 0; half < 2; ++half) {
        float acc[32];
        #pragma unroll
        for (int j = 0; j < 32; ++j) acc[j] = 0.f;
        #pragma unroll 1
        for (int kk = 0; kk < 8; ++kk) {
            const float4 r4 = row4[kk];
            const unsigned int p0 = packh2(r4.x, r4.y);
            const unsigned int p1 = packh2(r4.z, r4.w);
            const unsigned int* w = wp1 + kk * 128 + half * 32;
            #pragma unroll
            for (int j = 0; j < 32; ++j) acc[j] = dot2u(p0, w[j], acc[j]);
            #pragma unroll
            for (int j = 0; j < 32; ++j) acc[j] = dot2u(p1, w[64 + j], acc[j]);
        }
        #pragma unroll
        for (int p = 0; p < 16; ++p)
            hp[half * 16 + p][tid] = packh2(siluf(acc[2 * p] * INV_SQRT32),
                                            siluf(acc[2 * p + 1] * INV_SQRT32));
    }

    // ---- layer 2: h2 = silu((h1 @ W2)/8); stage halfA in regs until B done ----
    {
        unsigned int t16[16];
        {
            float acc[32];
            #pragma unroll
            for (int j = 0; j < 32; ++j) acc[j] = 0.f;
            #pragma unroll 4
            for (int k = 0; k < 32; ++k) {
                const unsigned int u = hp[k][tid];
                const unsigned int* w = wp2 + k * 64;
                #pragma unroll
                for (int j = 0; j < 32; ++j) acc[j] = dot2u(u, w[j], acc[j]);
            }
            #pragma unroll
            for (int p = 0; p < 16; ++p)
                t16[p] = packh2(siluf(acc[2 * p] * INV_8), siluf(acc[2 * p + 1] * INV_8));
        }
        {
            float acc[32];
            #pragma unroll
            for (int j = 0; j < 32; ++j) acc[j] = 0.f;
            #pragma unroll 4
            for (int k = 0; k < 32; ++k) {
                const unsigned int u = hp[k][tid];
                const unsigned int* w = wp2 + k * 64 + 32;
                #pragma unroll
                for (int j = 0; j < 32; ++j) acc[j] = dot2u(u, w[j], acc[j]);
            }
            #pragma unroll
            for (int p = 0; p < 16; ++p)
                hp[16 + p][tid] = packh2(siluf(acc[2 * p] * INV_8), siluf(acc[2 * p + 1] * INV_8));
        }
        #pragma unroll
        for (int p = 0; p < 16; ++p) hp[p][tid] = t16[p];
    }

    unsigned int* mp = msg + (size_t)ec * 128;
    float4 rv[8];
    #pragma unroll
    for (int i = 0; i < 8; ++i) rv[i] = row4[i];

    // ---- pass A half 0: mix[0:32] -> ch 0..31 ----
    {
        float acc[32];
        #pragma unroll
        for (int j = 0; j < 32; ++j) acc[j] = 0.f;
        #pragma unroll 4
        for (int k = 0; k < 32; ++k) {
            const unsigned int u = hp[k][tid];
            const unsigned int* w = wp3a + k * 64;
            #pragma unroll
            for (int j = 0; j < 32; ++j) acc[j] = dot2u(u, w[j], acc[j]);
        }
        unsigned int arr[16];
        #pragma unroll
        for (int w = 0; w < 16; ++w) {
            const int c0 = 2 * w, c1 = c0 + 1;
            const float a = f4c(rv[c0 >> 2], c0 & 3) * s0 * acc[c0] * (INV_8 * SCALE);
            const float b = f4c(rv[c1 >> 2], c1 & 3) * s0 * acc[c1] * (INV_8 * SCALE);
            arr[w] = pack2(a, b);
        }
        if (valid) {
            #pragma unroll
            for (int q = 0; q < 4; ++q)
                st4(mp + q * 4, arr[4 * q], arr[4 * q + 1], arr[4 * q + 2], arr[4 * q + 3]);
        }
    }

    // ---- pass A half 1: mix[32:64] -> ch 32..63 ----
    {
        float acc[32];
        #pragma unroll
        for (int j = 0; j < 32; ++j) acc[j] = 0.f;
        #pragma unroll 4
        for (int k = 0; k < 32; ++k) {
            const unsigned int u = hp[k][tid];
            const unsigned int* w = wp3a + k * 64 + 32;
            #pragma unroll
            for (int j = 0; j < 32; ++j) acc[j] = dot2u(u, w[j], acc[j]);
        }
        unsigned int arr[16];
        #pragma unroll
        for (int g = 0; g < 8; ++g) {           // ch 32..63: dot(v_j,v0)/sqrt3 * mix
            const float4 q0 = row4[8 + 3 * g], q1 = row4[8 + 3 * g + 1], q2 = row4[8 + 3 * g + 2];
            const float d0 = q0.x * v0x + q0.y * v0y + q0.z * v0z;
            const float d1 = q0.w * v0x + q1.x * v0y + q1.y * v0z;
            const float d2 = q1.z * v0x + q1.w * v0y + q2.x * v0z;
            const float d3 = q2.y * v0x + q2.z * v0y + q2.w * v0z;
            const float sc = INV_8 * SCALE * INV_SQRT3;
            arr[2 * g]     = pack2(d0 * acc[4 * g] * sc,     d1 * acc[4 * g + 1] * sc);
            arr[2 * g + 1] = pack2(d2 * acc[4 * g + 2] * sc, d3 * acc[4 * g + 3] * sc);
        }
        if (valid) {
            #pragma unroll
            for (int q = 0; q < 4; ++q)
                st4(mp + 16 + q * 4, arr[4 * q], arr[4 * q + 1], arr[4 * q + 2], arr[4 * q + 3]);
        }
    }

    // ---- pass B half 0: mix[64:96] -> ch 64..159 ----
    {
        float acc[32];
        #pragma unroll
        for (int j = 0; j < 32; ++j) acc[j] = 0.f;
        #pragma unroll 4
        for (int k = 0; k < 32; ++k) {
            const unsigned int u = hp[k][tid];
            const unsigned int* w = wp3b + k * 64;
            #pragma unroll
            for (int j = 0; j < 32; ++j) acc[j] = dot2u(u, w[j], acc[j]);
        }
        unsigned int arr[48];
        #pragma unroll
        for (int w = 0; w < 48; ++w) {          // s_j * v0_d * mix[64+j], f = 3j+d
            const int f0 = 2 * w, f1 = f0 + 1;
            const int j0 = f0 / 3, dd0 = f0 % 3, j1 = f1 / 3, dd1 = f1 % 3;
            const float a = f4c(rv[j0 >> 2], j0 & 3) * acc[j0] * (INV_8 * SCALE) *
                            (dd0 == 0 ? v0x : dd0 == 1 ? v0y : v0z);
            const float b = f4c(rv[j1 >> 2], j1 & 3) * acc[j1] * (INV_8 * SCALE) *
                            (dd1 == 0 ? v0x : dd1 == 1 ? v0y : v0z);
            arr[w] = pack2(a, b);
        }
        if (valid) {
            #pragma unroll
            for (int q = 0; q < 12; ++q)
                st4(mp + 32 + q * 4, arr[4 * q], arr[4 * q + 1], arr[4 * q + 2], arr[4 * q + 3]);
        }
    }

    // ---- pass B half 1: mix[96:128] -> ch 160..255 ----
    {
        float acc[32];
        #pragma unroll
        for (int j = 0; j < 32; ++j) acc[j] = 0.f;
        #pragma unroll 4
        for (int k = 0; k < 32; ++k) {
            const unsigned int u = hp[k][tid];
            const unsigned int* w = wp3b + k * 64 + 32;
            #pragma unroll
            for (int j = 0; j < 32; ++j) acc[j] = dot2u(u, w[j], acc[j]);
        }
        unsigned int arr[48];
        #pragma unroll
        for (int g = 0; g < 8; ++g) {           // v_j[d] * s0 * mix[96+j2]
            const float4 q0 = row4[8 + 3 * g], q1 = row4[8 + 3 * g + 1], q2 = row4[8 + 3 * g + 2];
            const float f[12] = {q0.x, q0.y, q0.z, q0.w, q1.x, q1.y, q1.z, q1.w,
                                 q2.x, q2.y, q2.z, q2.w};
            #pragma unroll
            for (int p = 0; p < 6; ++p) {
                const int i0 = 2 * p, i1 = i0 + 1;
                const float a = f[i0] * s0 * acc[(g * 12 + i0) / 3] * (INV_8 * SCALE);
                const float b = f[i1] * s0 * acc[(g * 12 + i1) / 3] * (INV_8 * SCALE);
                arr[6 * g + p] = pack2(a, b);
            }
        }
        if (valid) {
            #pragma unroll
            for (int q = 0; q < 12; ++q)
                st4(mp + 80 + q * 4, arr[4 * q], arr[4 * q + 1], arr[4 * q + 2], arr[4 * q + 3]);
        }
    }
}

// ---------------- Phase 2: gather (wave per node, lane = 4 channels) ----------------
__global__ __launch_bounds__(256) void gather_kernel(
    const unsigned short* __restrict__ msg, const int* __restrict__ off,
    const int* __restrict__ perm, float* __restrict__ out, int N)
{
    const int wid = threadIdx.x >> 6;
    const int lane = threadIdx.x & 63;
    const int n = blockIdx.x * 4 + wid;
    if (n >= N) return;
    const int beg = off[n], end = off[n + 1];
    float a0 = 0.f, a1 = 0.f, a2 = 0.f, a3 = 0.f;
    int i = beg;
    for (; i + 1 < end; i += 2) {
        const int e1 = perm[i], e2 = perm[i + 1];
        const u32x2 va = *(const u32x2*)(msg + (size_t)e1 * 256 + lane * 4);
        const u32x2 vb = *(const u32x2*)(msg + (size_t)e2 * 256 + lane * 4);
        a0 += bl(va[0]) + bl(vb[0]);
        a1 += bh(va[0]) + bh(vb[0]);
        a2 += bl(va[1]) + bl(vb[1]);
        a3 += bh(va[1]) + bh(vb[1]);
    }
    if (i < end) {
        const int e1 = perm[i];
        const u32x2 va = *(const u32x2*)(msg + (size_t)e1 * 256 + lane * 4);
        a0 += bl(va[0]); a1 += bh(va[0]); a2 += bl(va[1]); a3 += bh(va[1]);
    }
    *(float4*)(out + (size_t)n * NCH + lane * 4) = make_float4(a0, a1, a2, a3);
}

// ---------------- Fallback (atomic path, if ws too small) ----------------
__global__ __launch_bounds__(256, 2) void mpconv_atomic_kernel(
    const float* __restrict__ edge_feats, const float* __restrict__ edge_attrs,
    const int* __restrict__ receivers,
    const float* __restrict__ W1, const float* __restrict__ W2, const float* __restrict__ W3,
    float* __restrict__ out, int E)
{
    __shared__ float hbuf[64][256];
    const int tid = threadIdx.x;
    const int e = blockIdx.x * 256 + tid;
    if (e >= E) return;
    const float* row = edge_feats + (size_t)e * 128;
    float acc[64];
    #pragma unroll
    for (int j = 0; j < 64; ++j) acc[j] = 0.f;
    for (int k = 0; k < 32; ++k) {
        const float sk = row[k];
        const float* w = W1 + k * 64;
        #pragma unroll
        for (int j = 0; j < 64; ++j) acc[j] = fmaf(sk, w[j], acc[j]);
    }
    #pragma unroll
    for (int j = 0; j < 64; ++j) {
        const float x = acc[j] * INV_SQRT32;
        hbuf[j][tid] = x / (1.f + __expf(-x));
    }
    #pragma unroll
    for (int j = 0; j < 64; ++j) acc[j] = 0.f;
    for (int k = 0; k < 64; ++k) {
        const float hk = hbuf[k][tid];
        const float* w = W2 + k * 64;
        #pragma unroll
        for (int j = 0; j < 64; ++j) acc[j] = fmaf(hk, w[j], acc[j]);
    }
    #pragma unroll
    for (int j = 0; j < 64; ++j) {
        const float x = acc[j] * INV_8;
        hbuf[j][tid] = x / (1.f + __expf(-x));
    }
    const float4 ea = *reinterpret_cast<const float4*>(edge_attrs + (size_t)e * 4);
    const float s0 = ea.x, v0x = ea.y, v0y = ea.z, v0z = ea.w;
    const int r = receivers[e];
    float* o = out + (size_t)r * NCH;
    #pragma unroll
    for (int j = 0; j < 64; ++j) acc[j] = 0.f;
    for (int k = 0; k < 64; ++k) {
        const float hk = hbuf[k][tid];
        const float* w = W3 + k * 128;
        #pragma unroll
        for (int j = 0; j < 64; ++j) acc[j] = fmaf(hk, w[j], acc[j]);
    }
    #pragma unroll
    for (int j = 0; j < 32; ++j)
        unsafeAtomicAdd(o + j, row[j] * s0 * acc[j] * (INV_8 * SCALE));
    #pragma unroll
    for (int j = 32; j < 64; ++j) {
        const float* vr = row + 32 + (j - 32) * 3;
        const float dot = vr[0] * v0x + vr[1] * v0y + vr[2] * v0z;
        unsafeAtomicAdd(o + j, dot * acc[j] * (INV_8 * SCALE * INV_SQRT3));
    }
    #pragma unroll
    for (int j = 0; j < 64; ++j) acc[j] = 0.f;
    for (int k = 0; k < 64; ++k) {
        const float hk = hbuf[k][tid];
        const float* w = W3 + k * 128 + 64;
        #pragma unroll
        for (int j = 0; j < 64; ++j) acc[j] = fmaf(hk, w[j], acc[j]);
    }
    #pragma unroll
    for (int j = 0; j < 32; ++j) {
        const float sj = row[j] * acc[j] * (INV_8 * SCALE);
        unsafeAtomicAdd(o + 64 + j * 3 + 0, sj * v0x);
        unsafeAtomicAdd(o + 64 + j * 3 + 1, sj * v0y);
        unsafeAtomicAdd(o + 64 + j * 3 + 2, sj * v0z);
    }
    #pragma unroll
    for (int j = 32; j < 64; ++j) {
        const float m = acc[j] * (INV_8 * SCALE) * s0;
        const float* vr = row + 32 + (j - 32) * 3;
        unsafeAtomicAdd(o + 64 + j * 3 + 0, vr[0] * m);
        unsafeAtomicAdd(o + 64 + j * 3 + 1, vr[1] * m);
        unsafeAtomicAdd(o + 64 + j * 3 + 2, vr[2] * m);
    }
}

extern "C" void kernel_launch(void* const* d_in, const int* in_sizes, int n_in,
                              void* d_out, int out_size, void* d_ws, size_t ws_size,
                              hipStream_t stream) {
    const float* edge_feats = (const float*)d_in[0];
    const float* edge_attrs = (const float*)d_in[1];
    const int*   receivers  = (const int*)d_in[2];
    const float* W1 = (const float*)d_in[4];
    const float* W2 = (const float*)d_in[5];
    const float* W3 = (const float*)d_in[6];

    const int E = in_sizes[0] / 128;
    const int N = out_size / NCH;

    const size_t wb_bytes  = 7168 * sizeof(unsigned int);
    const size_t msg_bytes = (size_t)E * NCH * sizeof(unsigned short); // bf16
    const size_t need = wb_bytes + msg_bytes + (size_t)(3 * N + 1 + E) * sizeof(int);

    if (ws_size >= need) {
        unsigned int* wp  = (unsigned int*)d_ws;
        unsigned int* msg = (unsigned int*)((char*)d_ws + wb_bytes);
        int* cnt    = (int*)((char*)msg + msg_bytes);
        int* cursor = cnt + N;
        int* off    = cursor + N;
        int* perm   = off + N + 1;

        wconv_kernel<<<28, 256, 0, stream>>>(W1, W2, W3, wp);
        hipMemsetAsync(cnt, 0, (size_t)2 * N * sizeof(int), stream);
        hist_kernel<<<(E + 255) / 256, 256, 0, stream>>>(receivers, cnt, E);
        scan_kernel<<<1, 1024, 0, stream>>>(cnt, off, N);
        msg_kernel<<<(E + 255) / 256, 256, 0, stream>>>(
            edge_feats, edge_attrs, receivers, wp,
            off, cursor, perm, msg, E);
        gather_kernel<<<(N + 3) / 4, 256, 0, stream>>>(
            (const unsigned short*)msg, off, perm, (float*)d_out, N);
    } else {
        hipMemsetAsync(d_out, 0, (size_t)out_size * sizeof(float), stream);
        mpconv_atomic_kernel<<<(E + 255) / 256, 256, 0, stream>>>(
            edge_feats, edge_attrs, receivers, W1, W2, W3, (float*)d_out, E);
    }
}

// Round 18
// 433.707 us; speedup vs baseline: 3.2123x; 1.0094x over previous
//
#include <hip/hip_runtime.h>
#include <stdint.h>

// MessagePassingConvolution: E=500000, N=25000, C=32.
// Round 17: r16 (32-wide half-passes, best: 437.8us total, msg 333us) with
// ONE knob: __launch_bounds__(256,2) -> (256,4). r16 needs ~84 VGPR peak;
// cap 128 is safe (r7/r9/r12 regressions were caps < need). Expect 4
// blocks/CU resident (LDS 32KB allows 5, VGPR 68 allows 7 waves/SIMD).
// Guard metric: FETCH_SIZE must stay ~252MB (no spill).

#define NCH 256

constexpr float INV_SQRT32 = 0.17677669529663687f; // 1/sqrt(32)
constexpr float INV_8      = 0.125f;               // 1/sqrt(64)
constexpr float INV_SQRT3  = 0.57735026918962576f;
constexpr float SCALE      = 0.22360679774997896f; // 1/sqrt(20)

typedef _Float16 h2_t __attribute__((ext_vector_type(2)));
typedef unsigned int u32x4 __attribute__((ext_vector_type(4)));
typedef unsigned int u32x2 __attribute__((ext_vector_type(2)));

__device__ __forceinline__ float f4c(const float4 v, int c) {
    return c == 0 ? v.x : c == 1 ? v.y : c == 2 ? v.z : v.w;
}
__device__ __forceinline__ float bl(unsigned int u) { return __uint_as_float(u << 16); }
__device__ __forceinline__ float bh(unsigned int u) { return __uint_as_float(u & 0xffff0000u); }

__device__ __forceinline__ unsigned int pack2(float a, float b) {
    unsigned int r;
    asm("v_cvt_pk_bf16_f32 %0, %1, %2" : "=v"(r) : "v"(a), "v"(b));
    return r;
}
__device__ __forceinline__ unsigned int packh2(float a, float b) {
    return __builtin_bit_cast(unsigned int, __builtin_amdgcn_cvt_pkrtz(a, b));
}
__device__ __forceinline__ unsigned int packh2_rne(float a, float b) {
    h2_t v; v[0] = (_Float16)a; v[1] = (_Float16)b;
    return __builtin_bit_cast(unsigned int, v);
}
__device__ __forceinline__ float dot2u(unsigned int a, unsigned int b, float c) {
#if __has_builtin(__builtin_amdgcn_fdot2)
    return __builtin_amdgcn_fdot2(__builtin_bit_cast(h2_t, a),
                                  __builtin_bit_cast(h2_t, b), c, false);
#else
    h2_t x = __builtin_bit_cast(h2_t, a), y = __builtin_bit_cast(h2_t, b);
    return fmaf((float)x[0], (float)y[0], fmaf((float)x[1], (float)y[1], c));
#endif
}
__device__ __forceinline__ float siluf(float x) {
    const float d = 1.f + __expf(-x);
#if __has_builtin(__builtin_amdgcn_rcpf)
    return x * __builtin_amdgcn_rcpf(d);
#else
    return x / d;
#endif
}
__device__ __forceinline__ void st4(unsigned int* p, unsigned int a,
                                    unsigned int b, unsigned int c, unsigned int d) {
    u32x4 v; v[0] = a; v[1] = b; v[2] = c; v[3] = d;
    *(u32x4*)p = v;
}

// ---------------- weight pre-pack: f32 -> f16 pairs along K ----------------
// wp layout: [0,1024) W1p(16x64)  [1024,3072) W2p(32x64)
//            [3072,5120) W3A(32x64 = W3 cols 0..63)  [5120,7168) W3B(cols 64..127)
__global__ void wconv_kernel(const float* __restrict__ W1, const float* __restrict__ W2,
                             const float* __restrict__ W3, unsigned int* __restrict__ wp) {
    int t = blockIdx.x * 256 + threadIdx.x;
    if (t < 1024) {
        int k = t >> 6, j = t & 63;
        wp[t] = packh2_rne(W1[2 * k * 64 + j], W1[(2 * k + 1) * 64 + j]);
    } else if (t < 3072) {
        int i = t - 1024, k = i >> 6, j = i & 63;
        wp[t] = packh2_rne(W2[2 * k * 64 + j], W2[(2 * k + 1) * 64 + j]);
    } else if (t < 5120) {
        int i = t - 3072, k = i >> 6, j = i & 63;
        wp[t] = packh2_rne(W3[2 * k * 128 + j], W3[(2 * k + 1) * 128 + j]);
    } else if (t < 7168) {
        int i = t - 5120, k = i >> 6, j = i & 63;
        wp[t] = packh2_rne(W3[2 * k * 128 + 64 + j], W3[(2 * k + 1) * 128 + 64 + j]);
    }
}

// ---------------- CSR build ----------------
__global__ void hist_kernel(const int* __restrict__ recv, int* __restrict__ cnt, int E) {
    int e = blockIdx.x * 256 + threadIdx.x;
    if (e < E) atomicAdd(&cnt[recv[e]], 1);
}

__global__ __launch_bounds__(1024) void scan_kernel(const int* __restrict__ cnt,
                                                    int* __restrict__ off, int N) {
    __shared__ int sh[1024];
    __shared__ int sbase;
    if (threadIdx.x == 0) sbase = 0;
    __syncthreads();
    for (int base = 0; base < N; base += 1024) {
        int i = base + threadIdx.x;
        int v = (i < N) ? cnt[i] : 0;
        sh[threadIdx.x] = v;
        __syncthreads();
        #pragma unroll
        for (int d = 1; d < 1024; d <<= 1) {
            int t = (threadIdx.x >= d) ? sh[threadIdx.x - d] : 0;
            __syncthreads();
            sh[threadIdx.x] += t;
            __syncthreads();
        }
        int incl = sh[threadIdx.x];
        int bb = sbase;
        if (i < N) off[i] = bb + incl - v;
        __syncthreads();
        if (threadIdx.x == 1023) sbase = bb + incl;
        __syncthreads();
    }
    if (threadIdx.x == 0) off[N] = sbase;
}

// ---------------- Phase 1: f16-dot2 MLP (32-wide half passes) ----------------
__global__ __launch_bounds__(256, 4) void msg_kernel(
    const float* __restrict__ edge_feats,   // (E,128)
    const float* __restrict__ edge_attrs,   // (E,4)
    const int*   __restrict__ receivers,
    const unsigned int* __restrict__ wp,    // packed f16 weights
    const int* __restrict__ off, int* __restrict__ cursor, int* __restrict__ perm,
    unsigned int* __restrict__ msg,         // (E,128) u32 = 256 bf16 channels
    int E)
{
    __shared__ unsigned int hp[32][256];    // h as f16 pairs, 32 KB, thread-private cols

    const unsigned int* wp1  = wp;
    const unsigned int* wp2  = wp + 1024;
    const unsigned int* wp3a = wp + 3072;
    const unsigned int* wp3b = wp + 5120;

    const int tid = threadIdx.x;
    const int e = blockIdx.x * 256 + tid;
    const bool valid = (e < E);
    const int ec = valid ? e : (E - 1);
    const float4* row4 = (const float4*)(edge_feats + (size_t)ec * 128);

    const float4 ea = *(const float4*)(edge_attrs + (size_t)ec * 4);
    const float s0 = ea.x, v0x = ea.y, v0y = ea.z, v0z = ea.w;

    if (valid) {
        const int r = receivers[e];
        const int pos = off[r] + atomicAdd(&cursor[r], 1);
        perm[pos] = e;
    }

    // ---- layer 1: h1 = silu((s @ W1)/sqrt(32)), two 32-col halves ----
    #pragma unroll
    for (int half = 0; half < 2; ++half) {
        float acc[32];
        #pragma unroll
        for (int j = 0; j < 32; ++j) acc[j] = 0.f;
        #pragma unroll 1
        for (int kk = 0; kk < 8; ++kk) {
            const float4 r4 = row4[kk];
            const unsigned int p0 = packh2(r4.x, r4.y);
            const unsigned int p1 = packh2(r4.z, r4.w);
            const unsigned int* w = wp1 + kk * 128 + half * 32;
            #pragma unroll
            for (int j = 0; j < 32; ++j) acc[j] = dot2u(p0, w[j], acc[j]);
            #pragma unroll
            for (int j = 0; j < 32; ++j) acc[j] = dot2u(p1, w[64 + j], acc[j]);
        }
        #pragma unroll
        for (int p = 0; p < 16; ++p)
            hp[half * 16 + p][tid] = packh2(siluf(acc[2 * p] * INV_SQRT32),
                                            siluf(acc[2 * p + 1] * INV_SQRT32));
    }

    // ---- layer 2: h2 = silu((h1 @ W2)/8); stage halfA in regs until B done ----
    {
        unsigned int t16[16];
        {
            float acc[32];
            #pragma unroll
            for (int j = 0; j < 32; ++j) acc[j] = 0.f;
            #pragma unroll 4
            for (int k = 0; k < 32; ++k) {
                const unsigned int u = hp[k][tid];
                const unsigned int* w = wp2 + k * 64;
                #pragma unroll
                for (int j = 0; j < 32; ++j) acc[j] = dot2u(u, w[j], acc[j]);
            }
            #pragma unroll
            for (int p = 0; p < 16; ++p)
                t16[p] = packh2(siluf(acc[2 * p] * INV_8), siluf(acc[2 * p + 1] * INV_8));
        }
        {
            float acc[32];
            #pragma unroll
            for (int j = 0; j < 32; ++j) acc[j] = 0.f;
            #pragma unroll 4
            for (int k = 0; k < 32; ++k) {
                const unsigned int u = hp[k][tid];
                const unsigned int* w = wp2 + k * 64 + 32;
                #pragma unroll
                for (int j = 0; j < 32; ++j) acc[j] = dot2u(u, w[j], acc[j]);
            }
            #pragma unroll
            for (int p = 0; p < 16; ++p)
                hp[16 + p][tid] = packh2(siluf(acc[2 * p] * INV_8), siluf(acc[2 * p + 1] * INV_8));
        }
        #pragma unroll
        for (int p = 0; p < 16; ++p) hp[p][tid] = t16[p];
    }

    unsigned int* mp = msg + (size_t)ec * 128;
    float4 rv[8];
    #pragma unroll
    for (int i = 0; i < 8; ++i) rv[i] = row4[i];

    // ---- pass A half 0: mix[0:32] -> ch 0..31 ----
    {
        float acc[32];
        #pragma unroll
        for (int j = 0; j < 32; ++j) acc[j] = 0.f;
        #pragma unroll 4
        for (int k = 0; k < 32; ++k) {
            const unsigned int u = hp[k][tid];
            const unsigned int* w = wp3a + k * 64;
            #pragma unroll
            for (int j = 0; j < 32; ++j) acc[j] = dot2u(u, w[j], acc[j]);
        }
        unsigned int arr[16];
        #pragma unroll
        for (int w = 0; w < 16; ++w) {
            const int c0 = 2 * w, c1 = c0 + 1;
            const float a = f4c(rv[c0 >> 2], c0 & 3) * s0 * acc[c0] * (INV_8 * SCALE);
            const float b = f4c(rv[c1 >> 2], c1 & 3) * s0 * acc[c1] * (INV_8 * SCALE);
            arr[w] = pack2(a, b);
        }
        if (valid) {
            #pragma unroll
            for (int q = 0; q < 4; ++q)
                st4(mp + q * 4, arr[4 * q], arr[4 * q + 1], arr[4 * q + 2], arr[4 * q + 3]);
        }
    }

    // ---- pass A half 1: mix[32:64] -> ch 32..63 ----
    {
        float acc[32];
        #pragma unroll
        for (int j = 0; j < 32; ++j) acc[j] = 0.f;
        #pragma unroll 4
        for (int k = 0; k < 32; ++k) {
            const unsigned int u = hp[k][tid];
            const unsigned int* w = wp3a + k * 64 + 32;
            #pragma unroll
            for (int j = 0; j < 32; ++j) acc[j] = dot2u(u, w[j], acc[j]);
        }
        unsigned int arr[16];
        #pragma unroll
        for (int g = 0; g < 8; ++g) {           // ch 32..63: dot(v_j,v0)/sqrt3 * mix
            const float4 q0 = row4[8 + 3 * g], q1 = row4[8 + 3 * g + 1], q2 = row4[8 + 3 * g + 2];
            const float d0 = q0.x * v0x + q0.y * v0y + q0.z * v0z;
            const float d1 = q0.w * v0x + q1.x * v0y + q1.y * v0z;
            const float d2 = q1.z * v0x + q1.w * v0y + q2.x * v0z;
            const float d3 = q2.y * v0x + q2.z * v0y + q2.w * v0z;
            const float sc = INV_8 * SCALE * INV_SQRT3;
            arr[2 * g]     = pack2(d0 * acc[4 * g] * sc,     d1 * acc[4 * g + 1] * sc);
            arr[2 * g + 1] = pack2(d2 * acc[4 * g + 2] * sc, d3 * acc[4 * g + 3] * sc);
        }
        if (valid) {
            #pragma unroll
            for (int q = 0; q < 4; ++q)
                st4(mp + 16 + q * 4, arr[4 * q], arr[4 * q + 1], arr[4 * q + 2], arr[4 * q + 3]);
        }
    }

    // ---- pass B half 0: mix[64:96] -> ch 64..159 ----
    {
        float acc[32];
        #pragma unroll
        for (int j = 0; j < 32; ++j) acc[j] = 0.f;
        #pragma unroll 4
        for (int k = 0; k < 32; ++k) {
            const unsigned int u = hp[k][tid];
            const unsigned int* w = wp3b + k * 64;
            #pragma unroll
            for (int j = 0; j < 32; ++j) acc[j] = dot2u(u, w[j], acc[j]);
        }
        unsigned int arr[48];
        #pragma unroll
        for (int w = 0; w < 48; ++w) {          // s_j * v0_d * mix[64+j], f = 3j+d
            const int f0 = 2 * w, f1 = f0 + 1;
            const int j0 = f0 / 3, dd0 = f0 % 3, j1 = f1 / 3, dd1 = f1 % 3;
            const float a = f4c(rv[j0 >> 2], j0 & 3) * acc[j0] * (INV_8 * SCALE) *
                            (dd0 == 0 ? v0x : dd0 == 1 ? v0y : v0z);
            const float b = f4c(rv[j1 >> 2], j1 & 3) * acc[j1] * (INV_8 * SCALE) *
                            (dd1 == 0 ? v0x : dd1 == 1 ? v0y : v0z);
            arr[w] = pack2(a, b);
        }
        if (valid) {
            #pragma unroll
            for (int q = 0; q < 12; ++q)
                st4(mp + 32 + q * 4, arr[4 * q], arr[4 * q + 1], arr[4 * q + 2], arr[4 * q + 3]);
        }
    }

    // ---- pass B half 1: mix[96:128] -> ch 160..255 ----
    {
        float acc[32];
        #pragma unroll
        for (int j = 0; j < 32; ++j) acc[j] = 0.f;
        #pragma unroll 4
        for (int k = 0; k < 32; ++k) {
            const unsigned int u = hp[k][tid];
            const unsigned int* w = wp3b + k * 64 + 32;
            #pragma unroll
            for (int j = 0; j < 32; ++j) acc[j] = dot2u(u, w[j], acc[j]);
        }
        unsigned int arr[48];
        #pragma unroll
        for (int g = 0; g < 8; ++g) {           // v_j[d] * s0 * mix[96+j2]
            const float4 q0 = row4[8 + 3 * g], q1 = row4[8 + 3 * g + 1], q2 = row4[8 + 3 * g + 2];
            const float f[12] = {q0.x, q0.y, q0.z, q0.w, q1.x, q1.y, q1.z, q1.w,
                                 q2.x, q2.y, q2.z, q2.w};
            #pragma unroll
            for (int p = 0; p < 6; ++p) {
                const int i0 = 2 * p, i1 = i0 + 1;
                const float a = f[i0] * s0 * acc[(g * 12 + i0) / 3] * (INV_8 * SCALE);
                const float b = f[i1] * s0 * acc[(g * 12 + i1) / 3] * (INV_8 * SCALE);
                arr[6 * g + p] = pack2(a, b);
            }
        }
        if (valid) {
            #pragma unroll
            for (int q = 0; q < 12; ++q)
                st4(mp + 80 + q * 4, arr[4 * q], arr[4 * q + 1], arr[4 * q + 2], arr[4 * q + 3]);
        }
    }
}

// ---------------- Phase 2: gather (wave per node, lane = 4 channels) ----------------
__global__ __launch_bounds__(256) void gather_kernel(
    const unsigned short* __restrict__ msg, const int* __restrict__ off,
    const int* __restrict__ perm, float* __restrict__ out, int N)
{
    const int wid = threadIdx.x >> 6;
    const int lane = threadIdx.x & 63;
    const int n = blockIdx.x * 4 + wid;
    if (n >= N) return;
    const int beg = off[n], end = off[n + 1];
    float a0 = 0.f, a1 = 0.f, a2 = 0.f, a3 = 0.f;
    int i = beg;
    for (; i + 1 < end; i += 2) {
        const int e1 = perm[i], e2 = perm[i + 1];
        const u32x2 va = *(const u32x2*)(msg + (size_t)e1 * 256 + lane * 4);
        const u32x2 vb = *(const u32x2*)(msg + (size_t)e2 * 256 + lane * 4);
        a0 += bl(va[0]) + bl(vb[0]);
        a1 += bh(va[0]) + bh(vb[0]);
        a2 += bl(va[1]) + bl(vb[1]);
        a3 += bh(va[1]) + bh(vb[1]);
    }
    if (i < end) {
        const int e1 = perm[i];
        const u32x2 va = *(const u32x2*)(msg + (size_t)e1 * 256 + lane * 4);
        a0 += bl(va[0]); a1 += bh(va[0]); a2 += bl(va[1]); a3 += bh(va[1]);
    }
    *(float4*)(out + (size_t)n * NCH + lane * 4) = make_float4(a0, a1, a2, a3);
}

// ---------------- Fallback (atomic path, if ws too small) ----------------
__global__ __launch_bounds__(256, 2) void mpconv_atomic_kernel(
    const float* __restrict__ edge_feats, const float* __restrict__ edge_attrs,
    const int* __restrict__ receivers,
    const float* __restrict__ W1, const float* __restrict__ W2, const float* __restrict__ W3,
    float* __restrict__ out, int E)
{
    __shared__ float hbuf[64][256];
    const int tid = threadIdx.x;
    const int e = blockIdx.x * 256 + tid;
    if (e >= E) return;
    const float* row = edge_feats + (size_t)e * 128;
    float acc[64];
    #pragma unroll
    for (int j = 0; j < 64; ++j) acc[j] = 0.f;
    for (int k = 0; k < 32; ++k) {
        const float sk = row[k];
        const float* w = W1 + k * 64;
        #pragma unroll
        for (int j = 0; j < 64; ++j) acc[j] = fmaf(sk, w[j], acc[j]);
    }
    #pragma unroll
    for (int j = 0; j < 64; ++j) {
        const float x = acc[j] * INV_SQRT32;
        hbuf[j][tid] = x / (1.f + __expf(-x));
    }
    #pragma unroll
    for (int j = 0; j < 64; ++j) acc[j] = 0.f;
    for (int k = 0; k < 64; ++k) {
        const float hk = hbuf[k][tid];
        const float* w = W2 + k * 64;
        #pragma unroll
        for (int j = 0; j < 64; ++j) acc[j] = fmaf(hk, w[j], acc[j]);
    }
    #pragma unroll
    for (int j = 0; j < 64; ++j) {
        const float x = acc[j] * INV_8;
        hbuf[j][tid] = x / (1.f + __expf(-x));
    }
    const float4 ea = *reinterpret_cast<const float4*>(edge_attrs + (size_t)e * 4);
    const float s0 = ea.x, v0x = ea.y, v0y = ea.z, v0z = ea.w;
    const int r = receivers[e];
    float* o = out + (size_t)r * NCH;
    #pragma unroll
    for (int j = 0; j < 64; ++j) acc[j] = 0.f;
    for (int k = 0; k < 64; ++k) {
        const float hk = hbuf[k][tid];
        const float* w = W3 + k * 128;
        #pragma unroll
        for (int j = 0; j < 64; ++j) acc[j] = fmaf(hk, w[j], acc[j]);
    }
    #pragma unroll
    for (int j = 0; j < 32; ++j)
        unsafeAtomicAdd(o + j, row[j] * s0 * acc[j] * (INV_8 * SCALE));
    #pragma unroll
    for (int j = 32; j < 64; ++j) {
        const float* vr = row + 32 + (j - 32) * 3;
        const float dot = vr[0] * v0x + vr[1] * v0y + vr[2] * v0z;
        unsafeAtomicAdd(o + j, dot * acc[j] * (INV_8 * SCALE * INV_SQRT3));
    }
    #pragma unroll
    for (int j = 0; j < 64; ++j) acc[j] = 0.f;
    for (int k = 0; k < 64; ++k) {
        const float hk = hbuf[k][tid];
        const float* w = W3 + k * 128 + 64;
        #pragma unroll
        for (int j = 0; j < 64; ++j) acc[j] = fmaf(hk, w[j], acc[j]);
    }
    #pragma unroll
    for (int j = 0; j < 32; ++j) {
        const float sj = row[j] * acc[j] * (INV_8 * SCALE);
        unsafeAtomicAdd(o + 64 + j * 3 + 0, sj * v0x);
        unsafeAtomicAdd(o + 64 + j * 3 + 1, sj * v0y);
        unsafeAtomicAdd(o + 64 + j * 3 + 2, sj * v0z);
    }
    #pragma unroll
    for (int j = 32; j < 64; ++j) {
        const float m = acc[j] * (INV_8 * SCALE) * s0;
        const float* vr = row + 32 + (j - 32) * 3;
        unsafeAtomicAdd(o + 64 + j * 3 + 0, vr[0] * m);
        unsafeAtomicAdd(o + 64 + j * 3 + 1, vr[1] * m);
        unsafeAtomicAdd(o + 64 + j * 3 + 2, vr[2] * m);
    }
}

extern "C" void kernel_launch(void* const* d_in, const int* in_sizes, int n_in,
                              void* d_out, int out_size, void* d_ws, size_t ws_size,
                              hipStream_t stream) {
    const float* edge_feats = (const float*)d_in[0];
    const float* edge_attrs = (const float*)d_in[1];
    const int*   receivers  = (const int*)d_in[2];
    const float* W1 = (const float*)d_in[4];
    const float* W2 = (const float*)d_in[5];
    const float* W3 = (const float*)d_in[6];

    const int E = in_sizes[0] / 128;
    const int N = out_size / NCH;

    const size_t wb_bytes  = 7168 * sizeof(unsigned int);
    const size_t msg_bytes = (size_t)E * NCH * sizeof(unsigned short); // bf16
    const size_t need = wb_bytes + msg_bytes + (size_t)(3 * N + 1 + E) * sizeof(int);

    if (ws_size >= need) {
        unsigned int* wp  = (unsigned int*)d_ws;
        unsigned int* msg = (unsigned int*)((char*)d_ws + wb_bytes);
        int* cnt    = (int*)((char*)msg + msg_bytes);
        int* cursor = cnt + N;
        int* off    = cursor + N;
        int* perm   = off + N + 1;

        wconv_kernel<<<28, 256, 0, stream>>>(W1, W2, W3, wp);
        hipMemsetAsync(cnt, 0, (size_t)2 * N * sizeof(int), stream);
        hist_kernel<<<(E + 255) / 256, 256, 0, stream>>>(receivers, cnt, E);
        scan_kernel<<<1, 1024, 0, stream>>>(cnt, off, N);
        msg_kernel<<<(E + 255) / 256, 256, 0, stream>>>(
            edge_feats, edge_attrs, receivers, wp,
            off, cursor, perm, msg, E);
        gather_kernel<<<(N + 3) / 4, 256, 0, stream>>>(
            (const unsigned short*)msg, off, perm, (float*)d_out, N);
    } else {
        hipMemsetAsync(d_out, 0, (size_t)out_size * sizeof(float), stream);
        mpconv_atomic_kernel<<<(E + 255) / 256, 256, 0, stream>>>(
            edge_feats, edge_attrs, receivers, W1, W2, W3, (float*)d_out, E);
    }
}

// Round 19
// 397.356 us; speedup vs baseline: 3.5062x; 1.0915x over previous
//
#include <hip/hip_runtime.h>
#include <stdint.h>

// MessagePassingConvolution: E=500000, N=25000, C=32.
// Round 18: r17 (best: 433.7us; msg 319us) with the single-block serial
// scan replaced by a 3-dispatch parallel scan (25 blk in-block scan ->
// 1-thread block-sum scan -> fixup). Attacks the ~115us non-msg time;
// msg/gather/wconv/hist byte-identical to r17.

#define NCH 256

constexpr float INV_SQRT32 = 0.17677669529663687f; // 1/sqrt(32)
constexpr float INV_8      = 0.125f;               // 1/sqrt(64)
constexpr float INV_SQRT3  = 0.57735026918962576f;
constexpr float SCALE      = 0.22360679774997896f; // 1/sqrt(20)

typedef _Float16 h2_t __attribute__((ext_vector_type(2)));
typedef unsigned int u32x4 __attribute__((ext_vector_type(4)));
typedef unsigned int u32x2 __attribute__((ext_vector_type(2)));

__device__ __forceinline__ float f4c(const float4 v, int c) {
    return c == 0 ? v.x : c == 1 ? v.y : c == 2 ? v.z : v.w;
}
__device__ __forceinline__ float bl(unsigned int u) { return __uint_as_float(u << 16); }
__device__ __forceinline__ float bh(unsigned int u) { return __uint_as_float(u & 0xffff0000u); }

__device__ __forceinline__ unsigned int pack2(float a, float b) {
    unsigned int r;
    asm("v_cvt_pk_bf16_f32 %0, %1, %2" : "=v"(r) : "v"(a), "v"(b));
    return r;
}
__device__ __forceinline__ unsigned int packh2(float a, float b) {
    return __builtin_bit_cast(unsigned int, __builtin_amdgcn_cvt_pkrtz(a, b));
}
__device__ __forceinline__ unsigned int packh2_rne(float a, float b) {
    h2_t v; v[0] = (_Float16)a; v[1] = (_Float16)b;
    return __builtin_bit_cast(unsigned int, v);
}
__device__ __forceinline__ float dot2u(unsigned int a, unsigned int b, float c) {
#if __has_builtin(__builtin_amdgcn_fdot2)
    return __builtin_amdgcn_fdot2(__builtin_bit_cast(h2_t, a),
                                  __builtin_bit_cast(h2_t, b), c, false);
#else
    h2_t x = __builtin_bit_cast(h2_t, a), y = __builtin_bit_cast(h2_t, b);
    return fmaf((float)x[0], (float)y[0], fmaf((float)x[1], (float)y[1], c));
#endif
}
__device__ __forceinline__ float siluf(float x) {
    const float d = 1.f + __expf(-x);
#if __has_builtin(__builtin_amdgcn_rcpf)
    return x * __builtin_amdgcn_rcpf(d);
#else
    return x / d;
#endif
}
__device__ __forceinline__ void st4(unsigned int* p, unsigned int a,
                                    unsigned int b, unsigned int c, unsigned int d) {
    u32x4 v; v[0] = a; v[1] = b; v[2] = c; v[3] = d;
    *(u32x4*)p = v;
}

// ---------------- weight pre-pack: f32 -> f16 pairs along K ----------------
__global__ void wconv_kernel(const float* __restrict__ W1, const float* __restrict__ W2,
                             const float* __restrict__ W3, unsigned int* __restrict__ wp) {
    int t = blockIdx.x * 256 + threadIdx.x;
    if (t < 1024) {
        int k = t >> 6, j = t & 63;
        wp[t] = packh2_rne(W1[2 * k * 64 + j], W1[(2 * k + 1) * 64 + j]);
    } else if (t < 3072) {
        int i = t - 1024, k = i >> 6, j = i & 63;
        wp[t] = packh2_rne(W2[2 * k * 64 + j], W2[(2 * k + 1) * 64 + j]);
    } else if (t < 5120) {
        int i = t - 3072, k = i >> 6, j = i & 63;
        wp[t] = packh2_rne(W3[2 * k * 128 + j], W3[(2 * k + 1) * 128 + j]);
    } else if (t < 7168) {
        int i = t - 5120, k = i >> 6, j = i & 63;
        wp[t] = packh2_rne(W3[2 * k * 128 + 64 + j], W3[(2 * k + 1) * 128 + 64 + j]);
    }
}

// ---------------- CSR build ----------------
__global__ void hist_kernel(const int* __restrict__ recv, int* __restrict__ cnt, int E) {
    int e = blockIdx.x * 256 + threadIdx.x;
    if (e < E) atomicAdd(&cnt[recv[e]], 1);
}

// parallel scan, phase 1: per-block (1024 elems) exclusive scan + block sum
__global__ __launch_bounds__(256) void scan1_kernel(const int* __restrict__ cnt,
                                                    int* __restrict__ off,
                                                    int* __restrict__ bsum, int N) {
    __shared__ int sh[256];
    const int tid = threadIdx.x;
    const int base = blockIdx.x * 1024 + tid * 4;
    int v0 = (base + 0 < N) ? cnt[base + 0] : 0;
    int v1 = (base + 1 < N) ? cnt[base + 1] : 0;
    int v2 = (base + 2 < N) ? cnt[base + 2] : 0;
    int v3 = (base + 3 < N) ? cnt[base + 3] : 0;
    const int s = v0 + v1 + v2 + v3;
    sh[tid] = s;
    __syncthreads();
    #pragma unroll
    for (int d = 1; d < 256; d <<= 1) {
        int t = (tid >= d) ? sh[tid - d] : 0;
        __syncthreads();
        sh[tid] += t;
        __syncthreads();
    }
    int excl = sh[tid] - s;
    if (base + 0 < N) off[base + 0] = excl;  excl += v0;
    if (base + 1 < N) off[base + 1] = excl;  excl += v1;
    if (base + 2 < N) off[base + 2] = excl;  excl += v2;
    if (base + 3 < N) off[base + 3] = excl;
    if (tid == 255) bsum[blockIdx.x] = sh[255];
}

// phase 2: exclusive scan of block sums (nb <= ~32, serial in one thread)
__global__ void scan2_kernel(int* __restrict__ bsum, int nb) {
    if (blockIdx.x == 0 && threadIdx.x == 0) {
        int acc = 0;
        for (int i = 0; i < nb; ++i) { const int t = bsum[i]; bsum[i] = acc; acc += t; }
        bsum[nb] = acc;
    }
}

// phase 3: add block offset; write off[N]
__global__ __launch_bounds__(256) void scan3_kernel(int* __restrict__ off,
                                                    const int* __restrict__ bsum,
                                                    int N, int nb) {
    const int add = bsum[blockIdx.x];
    const int base = blockIdx.x * 1024 + threadIdx.x * 4;
    if (base + 0 < N) off[base + 0] += add;
    if (base + 1 < N) off[base + 1] += add;
    if (base + 2 < N) off[base + 2] += add;
    if (base + 3 < N) off[base + 3] += add;
    if (blockIdx.x == 0 && threadIdx.x == 0) off[N] = bsum[nb];
}

// ---------------- Phase 1: f16-dot2 MLP (32-wide half passes) ----------------
__global__ __launch_bounds__(256, 4) void msg_kernel(
    const float* __restrict__ edge_feats,   // (E,128)
    const float* __restrict__ edge_attrs,   // (E,4)
    const int*   __restrict__ receivers,
    const unsigned int* __restrict__ wp,    // packed f16 weights
    const int* __restrict__ off, int* __restrict__ cursor, int* __restrict__ perm,
    unsigned int* __restrict__ msg,         // (E,128) u32 = 256 bf16 channels
    int E)
{
    __shared__ unsigned int hp[32][256];    // h as f16 pairs, 32 KB, thread-private cols

    const unsigned int* wp1  = wp;
    const unsigned int* wp2  = wp + 1024;
    const unsigned int* wp3a = wp + 3072;
    const unsigned int* wp3b = wp + 5120;

    const int tid = threadIdx.x;
    const int e = blockIdx.x * 256 + tid;
    const bool valid = (e < E);
    const int ec = valid ? e : (E - 1);
    const float4* row4 = (const float4*)(edge_feats + (size_t)ec * 128);

    const float4 ea = *(const float4*)(edge_attrs + (size_t)ec * 4);
    const float s0 = ea.x, v0x = ea.y, v0y = ea.z, v0z = ea.w;

    if (valid) {
        const int r = receivers[e];
        const int pos = off[r] + atomicAdd(&cursor[r], 1);
        perm[pos] = e;
    }

    // ---- layer 1: h1 = silu((s @ W1)/sqrt(32)), two 32-col halves ----
    #pragma unroll
    for (int half = 0; half < 2; ++half) {
        float acc[32];
        #pragma unroll
        for (int j = 0; j < 32; ++j) acc[j] = 0.f;
        #pragma unroll 1
        for (int kk = 0; kk < 8; ++kk) {
            const float4 r4 = row4[kk];
            const unsigned int p0 = packh2(r4.x, r4.y);
            const unsigned int p1 = packh2(r4.z, r4.w);
            const unsigned int* w = wp1 + kk * 128 + half * 32;
            #pragma unroll
            for (int j = 0; j < 32; ++j) acc[j] = dot2u(p0, w[j], acc[j]);
            #pragma unroll
            for (int j = 0; j < 32; ++j) acc[j] = dot2u(p1, w[64 + j], acc[j]);
        }
        #pragma unroll
        for (int p = 0; p < 16; ++p)
            hp[half * 16 + p][tid] = packh2(siluf(acc[2 * p] * INV_SQRT32),
                                            siluf(acc[2 * p + 1] * INV_SQRT32));
    }

    // ---- layer 2: h2 = silu((h1 @ W2)/8); stage halfA in regs until B done ----
    {
        unsigned int t16[16];
        {
            float acc[32];
            #pragma unroll
            for (int j = 0; j < 32; ++j) acc[j] = 0.f;
            #pragma unroll 4
            for (int k = 0; k < 32; ++k) {
                const unsigned int u = hp[k][tid];
                const unsigned int* w = wp2 + k * 64;
                #pragma unroll
                for (int j = 0; j < 32; ++j) acc[j] = dot2u(u, w[j], acc[j]);
            }
            #pragma unroll
            for (int p = 0; p < 16; ++p)
                t16[p] = packh2(siluf(acc[2 * p] * INV_8), siluf(acc[2 * p + 1] * INV_8));
        }
        {
            float acc[32];
            #pragma unroll
            for (int j = 0; j < 32; ++j) acc[j] = 0.f;
            #pragma unroll 4
            for (int k = 0; k < 32; ++k) {
                const unsigned int u = hp[k][tid];
                const unsigned int* w = wp2 + k * 64 + 32;
                #pragma unroll
                for (int j = 0; j < 32; ++j) acc[j] = dot2u(u, w[j], acc[j]);
            }
            #pragma unroll
            for (int p = 0; p < 16; ++p)
                hp[16 + p][tid] = packh2(siluf(acc[2 * p] * INV_8), siluf(acc[2 * p + 1] * INV_8));
        }
        #pragma unroll
        for (int p = 0; p < 16; ++p) hp[p][tid] = t16[p];
    }

    unsigned int* mp = msg + (size_t)ec * 128;
    float4 rv[8];
    #pragma unroll
    for (int i = 0; i < 8; ++i) rv[i] = row4[i];

    // ---- pass A half 0: mix[0:32] -> ch 0..31 ----
    {
        float acc[32];
        #pragma unroll
        for (int j = 0; j < 32; ++j) acc[j] = 0.f;
        #pragma unroll 4
        for (int k = 0; k < 32; ++k) {
            const unsigned int u = hp[k][tid];
            const unsigned int* w = wp3a + k * 64;
            #pragma unroll
            for (int j = 0; j < 32; ++j) acc[j] = dot2u(u, w[j], acc[j]);
        }
        unsigned int arr[16];
        #pragma unroll
        for (int w = 0; w < 16; ++w) {
            const int c0 = 2 * w, c1 = c0 + 1;
            const float a = f4c(rv[c0 >> 2], c0 & 3) * s0 * acc[c0] * (INV_8 * SCALE);
            const float b = f4c(rv[c1 >> 2], c1 & 3) * s0 * acc[c1] * (INV_8 * SCALE);
            arr[w] = pack2(a, b);
        }
        if (valid) {
            #pragma unroll
            for (int q = 0; q < 4; ++q)
                st4(mp + q * 4, arr[4 * q], arr[4 * q + 1], arr[4 * q + 2], arr[4 * q + 3]);
        }
    }

    // ---- pass A half 1: mix[32:64] -> ch 32..63 ----
    {
        float acc[32];
        #pragma unroll
        for (int j = 0; j < 32; ++j) acc[j] = 0.f;
        #pragma unroll 4
        for (int k = 0; k < 32; ++k) {
            const unsigned int u = hp[k][tid];
            const unsigned int* w = wp3a + k * 64 + 32;
            #pragma unroll
            for (int j = 0; j < 32; ++j) acc[j] = dot2u(u, w[j], acc[j]);
        }
        unsigned int arr[16];
        #pragma unroll
        for (int g = 0; g < 8; ++g) {
            const float4 q0 = row4[8 + 3 * g], q1 = row4[8 + 3 * g + 1], q2 = row4[8 + 3 * g + 2];
            const float d0 = q0.x * v0x + q0.y * v0y + q0.z * v0z;
            const float d1 = q0.w * v0x + q1.x * v0y + q1.y * v0z;
            const float d2 = q1.z * v0x + q1.w * v0y + q2.x * v0z;
            const float d3 = q2.y * v0x + q2.z * v0y + q2.w * v0z;
            const float sc = INV_8 * SCALE * INV_SQRT3;
            arr[2 * g]     = pack2(d0 * acc[4 * g] * sc,     d1 * acc[4 * g + 1] * sc);
            arr[2 * g + 1] = pack2(d2 * acc[4 * g + 2] * sc, d3 * acc[4 * g + 3] * sc);
        }
        if (valid) {
            #pragma unroll
            for (int q = 0; q < 4; ++q)
                st4(mp + 16 + q * 4, arr[4 * q], arr[4 * q + 1], arr[4 * q + 2], arr[4 * q + 3]);
        }
    }

    // ---- pass B half 0: mix[64:96] -> ch 64..159 ----
    {
        float acc[32];
        #pragma unroll
        for (int j = 0; j < 32; ++j) acc[j] = 0.f;
        #pragma unroll 4
        for (int k = 0; k < 32; ++k) {
            const unsigned int u = hp[k][tid];
            const unsigned int* w = wp3b + k * 64;
            #pragma unroll
            for (int j = 0; j < 32; ++j) acc[j] = dot2u(u, w[j], acc[j]);
        }
        unsigned int arr[48];
        #pragma unroll
        for (int w = 0; w < 48; ++w) {
            const int f0 = 2 * w, f1 = f0 + 1;
            const int j0 = f0 / 3, dd0 = f0 % 3, j1 = f1 / 3, dd1 = f1 % 3;
            const float a = f4c(rv[j0 >> 2], j0 & 3) * acc[j0] * (INV_8 * SCALE) *
                            (dd0 == 0 ? v0x : dd0 == 1 ? v0y : v0z);
            const float b = f4c(rv[j1 >> 2], j1 & 3) * acc[j1] * (INV_8 * SCALE) *
                            (dd1 == 0 ? v0x : dd1 == 1 ? v0y : v0z);
            arr[w] = pack2(a, b);
        }
        if (valid) {
            #pragma unroll
            for (int q = 0; q < 12; ++q)
                st4(mp + 32 + q * 4, arr[4 * q], arr[4 * q + 1], arr[4 * q + 2], arr[4 * q + 3]);
        }
    }

    // ---- pass B half 1: mix[96:128] -> ch 160..255 ----
    {
        float acc[32];
        #pragma unroll
        for (int j = 0; j < 32; ++j) acc[j] = 0.f;
        #pragma unroll 4
        for (int k = 0; k < 32; ++k) {
            const unsigned int u = hp[k][tid];
            const unsigned int* w = wp3b + k * 64 + 32;
            #pragma unroll
            for (int j = 0; j < 32; ++j) acc[j] = dot2u(u, w[j], acc[j]);
        }
        unsigned int arr[48];
        #pragma unroll
        for (int g = 0; g < 8; ++g) {
            const float4 q0 = row4[8 + 3 * g], q1 = row4[8 + 3 * g + 1], q2 = row4[8 + 3 * g + 2];
            const float f[12] = {q0.x, q0.y, q0.z, q0.w, q1.x, q1.y, q1.z, q1.w,
                                 q2.x, q2.y, q2.z, q2.w};
            #pragma unroll
            for (int p = 0; p < 6; ++p) {
                const int i0 = 2 * p, i1 = i0 + 1;
                const float a = f[i0] * s0 * acc[(g * 12 + i0) / 3] * (INV_8 * SCALE);
                const float b = f[i1] * s0 * acc[(g * 12 + i1) / 3] * (INV_8 * SCALE);
                arr[6 * g + p] = pack2(a, b);
            }
        }
        if (valid) {
            #pragma unroll
            for (int q = 0; q < 12; ++q)
                st4(mp + 80 + q * 4, arr[4 * q], arr[4 * q + 1], arr[4 * q + 2], arr[4 * q + 3]);
        }
    }
}

// ---------------- Phase 2: gather (wave per node, lane = 4 channels) ----------------
__global__ __launch_bounds__(256) void gather_kernel(
    const unsigned short* __restrict__ msg, const int* __restrict__ off,
    const int* __restrict__ perm, float* __restrict__ out, int N)
{
    const int wid = threadIdx.x >> 6;
    const int lane = threadIdx.x & 63;
    const int n = blockIdx.x * 4 + wid;
    if (n >= N) return;
    const int beg = off[n], end = off[n + 1];
    float a0 = 0.f, a1 = 0.f, a2 = 0.f, a3 = 0.f;
    int i = beg;
    for (; i + 1 < end; i += 2) {
        const int e1 = perm[i], e2 = perm[i + 1];
        const u32x2 va = *(const u32x2*)(msg + (size_t)e1 * 256 + lane * 4);
        const u32x2 vb = *(const u32x2*)(msg + (size_t)e2 * 256 + lane * 4);
        a0 += bl(va[0]) + bl(vb[0]);
        a1 += bh(va[0]) + bh(vb[0]);
        a2 += bl(va[1]) + bl(vb[1]);
        a3 += bh(va[1]) + bh(vb[1]);
    }
    if (i < end) {
        const int e1 = perm[i];
        const u32x2 va = *(const u32x2*)(msg + (size_t)e1 * 256 + lane * 4);
        a0 += bl(va[0]); a1 += bh(va[0]); a2 += bl(va[1]); a3 += bh(va[1]);
    }
    *(float4*)(out + (size_t)n * NCH + lane * 4) = make_float4(a0, a1, a2, a3);
}

// ---------------- Fallback (atomic path, if ws too small) ----------------
__global__ __launch_bounds__(256, 2) void mpconv_atomic_kernel(
    const float* __restrict__ edge_feats, const float* __restrict__ edge_attrs,
    const int* __restrict__ receivers,
    const float* __restrict__ W1, const float* __restrict__ W2, const float* __restrict__ W3,
    float* __restrict__ out, int E)
{
    __shared__ float hbuf[64][256];
    const int tid = threadIdx.x;
    const int e = blockIdx.x * 256 + tid;
    if (e >= E) return;
    const float* row = edge_feats + (size_t)e * 128;
    float acc[64];
    #pragma unroll
    for (int j = 0; j < 64; ++j) acc[j] = 0.f;
    for (int k = 0; k < 32; ++k) {
        const float sk = row[k];
        const float* w = W1 + k * 64;
        #pragma unroll
        for (int j = 0; j < 64; ++j) acc[j] = fmaf(sk, w[j], acc[j]);
    }
    #pragma unroll
    for (int j = 0; j < 64; ++j) {
        const float x = acc[j] * INV_SQRT32;
        hbuf[j][tid] = x / (1.f + __expf(-x));
    }
    #pragma unroll
    for (int j = 0; j < 64; ++j) acc[j] = 0.f;
    for (int k = 0; k < 64; ++k) {
        const float hk = hbuf[k][tid];
        const float* w = W2 + k * 64;
        #pragma unroll
        for (int j = 0; j < 64; ++j) acc[j] = fmaf(hk, w[j], acc[j]);
    }
    #pragma unroll
    for (int j = 0; j < 64; ++j) {
        const float x = acc[j] * INV_8;
        hbuf[j][tid] = x / (1.f + __expf(-x));
    }
    const float4 ea = *reinterpret_cast<const float4*>(edge_attrs + (size_t)e * 4);
    const float s0 = ea.x, v0x = ea.y, v0y = ea.z, v0z = ea.w;
    const int r = receivers[e];
    float* o = out + (size_t)r * NCH;
    #pragma unroll
    for (int j = 0; j < 64; ++j) acc[j] = 0.f;
    for (int k = 0; k < 64; ++k) {
        const float hk = hbuf[k][tid];
        const float* w = W3 + k * 128;
        #pragma unroll
        for (int j = 0; j < 64; ++j) acc[j] = fmaf(hk, w[j], acc[j]);
    }
    #pragma unroll
    for (int j = 0; j < 32; ++j)
        unsafeAtomicAdd(o + j, row[j] * s0 * acc[j] * (INV_8 * SCALE));
    #pragma unroll
    for (int j = 32; j < 64; ++j) {
        const float* vr = row + 32 + (j - 32) * 3;
        const float dot = vr[0] * v0x + vr[1] * v0y + vr[2] * v0z;
        unsafeAtomicAdd(o + j, dot * acc[j] * (INV_8 * SCALE * INV_SQRT3));
    }
    #pragma unroll
    for (int j = 0; j < 64; ++j) acc[j] = 0.f;
    for (int k = 0; k < 64; ++k) {
        const float hk = hbuf[k][tid];
        const float* w = W3 + k * 128 + 64;
        #pragma unroll
        for (int j = 0; j < 64; ++j) acc[j] = fmaf(hk, w[j], acc[j]);
    }
    #pragma unroll
    for (int j = 0; j < 32; ++j) {
        const float sj = row[j] * acc[j] * (INV_8 * SCALE);
        unsafeAtomicAdd(o + 64 + j * 3 + 0, sj * v0x);
        unsafeAtomicAdd(o + 64 + j * 3 + 1, sj * v0y);
        unsafeAtomicAdd(o + 64 + j * 3 + 2, sj * v0z);
    }
    #pragma unroll
    for (int j = 32; j < 64; ++j) {
        const float m = acc[j] * (INV_8 * SCALE) * s0;
        const float* vr = row + 32 + (j - 32) * 3;
        unsafeAtomicAdd(o + 64 + j * 3 + 0, vr[0] * m);
        unsafeAtomicAdd(o + 64 + j * 3 + 1, vr[1] * m);
        unsafeAtomicAdd(o + 64 + j * 3 + 2, vr[2] * m);
    }
}

extern "C" void kernel_launch(void* const* d_in, const int* in_sizes, int n_in,
                              void* d_out, int out_size, void* d_ws, size_t ws_size,
                              hipStream_t stream) {
    const float* edge_feats = (const float*)d_in[0];
    const float* edge_attrs = (const float*)d_in[1];
    const int*   receivers  = (const int*)d_in[2];
    const float* W1 = (const float*)d_in[4];
    const float* W2 = (const float*)d_in[5];
    const float* W3 = (const float*)d_in[6];

    const int E = in_sizes[0] / 128;
    const int N = out_size / NCH;
    const int nb = (N + 1023) / 1024;

    const size_t wb_bytes  = 7168 * sizeof(unsigned int);
    const size_t msg_bytes = (size_t)E * NCH * sizeof(unsigned short); // bf16
    const size_t need = wb_bytes + msg_bytes +
                        (size_t)(3 * N + 1 + E + nb + 1) * sizeof(int);

    if (ws_size >= need) {
        unsigned int* wp  = (unsigned int*)d_ws;
        unsigned int* msg = (unsigned int*)((char*)d_ws + wb_bytes);
        int* cnt    = (int*)((char*)msg + msg_bytes);
        int* cursor = cnt + N;
        int* off    = cursor + N;
        int* perm   = off + N + 1;
        int* bsum   = perm + E;

        wconv_kernel<<<28, 256, 0, stream>>>(W1, W2, W3, wp);
        hipMemsetAsync(cnt, 0, (size_t)2 * N * sizeof(int), stream);
        hist_kernel<<<(E + 255) / 256, 256, 0, stream>>>(receivers, cnt, E);
        scan1_kernel<<<nb, 256, 0, stream>>>(cnt, off, bsum, N);
        scan2_kernel<<<1, 64, 0, stream>>>(bsum, nb);
        scan3_kernel<<<nb, 256, 0, stream>>>(off, bsum, N, nb);
        msg_kernel<<<(E + 255) / 256, 256, 0, stream>>>(
            edge_feats, edge_attrs, receivers, wp,
            off, cursor, perm, msg, E);
        gather_kernel<<<(N + 3) / 4, 256, 0, stream>>>(
            (const unsigned short*)msg, off, perm, (float*)d_out, N);
    } else {
        hipMemsetAsync(d_out, 0, (size_t)out_size * sizeof(float), stream);
        mpconv_atomic_kernel<<<(E + 255) / 256, 256, 0, stream>>>(
            edge_feats, edge_attrs, receivers, W1, W2, W3, (float*)d_out, E);
    }
}